// Round 1
// baseline (290.937 us; speedup 1.0000x reference)
//
#include <hip/hip_runtime.h>
#include <hip/hip_bf16.h>

// GCN. R-new: CSR build WITHOUT bucket sort. Key insight: CSR ranges need only be
// disjoint, not node-ordered. count_kernel's atomicAdd return value IS the edge's
// rank within its dst row (stored as 1 byte); reserve_kernel grabs per-256-node-block
// space with ONE global atomicAdd (order-free) + absorbs per-node work (rowbounds,
// dinv, pad fill, prescaled bf16 x-cast); place_kernel is an atomic-free scatter.
// This deletes the staged 8.4MB round-trip, ~33K LDS atomics/block and two LDS scans
// that the old bucket+build pair paid (~45-55 us modeled).
// Layer 1: agg over 4 MB bf16 x-table (L2-resident). Layer 2: single 8 MB fp8
// table (R17 showed splitting it doubles per-edge line requests). h1 LDS-only;
// w1w2 matmul register-tiled 4 nodes x 4 ch per thread over transposed h1.

#define N_NODES 131072
#define N_EDGES 2097152
#define N_GRAPHS 2048
#define IN_CH 12
#define HID 64
#define OUT_CH 4
#define CSR_CAP 2560000    // >= 2M + 3*131072 = 2,490,368 padded entries

typedef float f32x2 __attribute__((ext_vector_type(2)));

__device__ __forceinline__ unsigned short f2bf(float f) {
    unsigned u = __float_as_uint(f);
    return (unsigned short)((u + 0x7fffu + ((u >> 16) & 1u)) >> 16);  // RNE
}
__device__ __forceinline__ unsigned pack2bf(float lo, float hi) {
    return (unsigned)f2bf(lo) | ((unsigned)f2bf(hi) << 16);
}
__device__ __forceinline__ float bflo(unsigned v) { return __uint_as_float(v << 16); }
__device__ __forceinline__ float bfhi(unsigned v) { return __uint_as_float(v & 0xFFFF0000u); }

// ---- pass A: degree count; atomic return value = rank of edge within its row ----
__global__ void count_kernel(const int* __restrict__ dst, int* __restrict__ deg,
                             unsigned char* __restrict__ rank) {
    int i = (blockIdx.x * 256 + threadIdx.x) * 4;
    int4 d = *(const int4*)(dst + i);
    unsigned r0 = (unsigned)atomicAdd(&deg[d.x], 1);
    unsigned r1 = (unsigned)atomicAdd(&deg[d.y], 1);
    unsigned r2 = (unsigned)atomicAdd(&deg[d.z], 1);
    unsigned r3 = (unsigned)atomicAdd(&deg[d.w], 1);
    *(uchar4*)(rank + i) = make_uchar4((unsigned char)r0, (unsigned char)r1,
                                       (unsigned char)r2, (unsigned char)r3);
}

// ---- pass B: order-free space reservation (block scan + 1 global atomic) + per-node
//      work: rowbounds, dinv, csr pad fill, prescaled bf16 x-cast ----
__global__ void reserve_kernel(const int* __restrict__ deg, int* __restrict__ gcur,
                               int2* __restrict__ rowbounds, float* __restrict__ dinv,
                               int* __restrict__ csr, const float* __restrict__ x,
                               unsigned short* __restrict__ xb) {
    __shared__ int scn[256];
    __shared__ int sbase;
    int b = blockIdx.x, tid = threadIdx.x;
    int n = b * 256 + tid;
    int dg = deg[n];
    int degp = (dg + 3) & ~3;  // pad to x4 (int4 edge loads downstream)
    scn[tid] = degp;
    __syncthreads();
    for (int off = 1; off < 256; off <<= 1) {
        int u = (tid >= off) ? scn[tid - off] : 0;
        __syncthreads();
        scn[tid] += u;
        __syncthreads();
    }
    if (tid == 255) sbase = atomicAdd(gcur, scn[255]);
    __syncthreads();
    int lo = sbase + scn[tid] - degp;
    rowbounds[n] = make_int2(lo, lo + degp);
    float dv = rsqrtf((float)dg + 1.0f);
    dinv[n] = dv;
    int padval = N_NODES << 6;  // zero row
    for (int p = lo + dg; p < lo + degp; p++) csr[p] = padval;
    {   // prescaled x cast: xb[n] = bf16(dinv[n] * x[n]), padded to 16 ch
        const float* xp = x + n * IN_CH;
        unsigned o[8];
#pragma unroll
        for (int k = 0; k < 6; k++) o[k] = pack2bf(dv * xp[2 * k], dv * xp[2 * k + 1]);
        o[6] = 0; o[7] = 0;
        uint4* dstp = (uint4*)(xb + n * 16);
        dstp[0] = make_uint4(o[0], o[1], o[2], o[3]);
        dstp[1] = make_uint4(o[4], o[5], o[6], o[7]);
    }
    if (b == 0 && tid < 2)  // zero row N_NODES of xb (pad target)
        ((uint4*)(xb + (size_t)N_NODES * 16))[tid] = make_uint4(0, 0, 0, 0);
}

// ---- pass C: atomic-free placement scatter; same-row words are contiguous so L2
//      merges the 4B stores ----
__global__ void place_kernel(const int* __restrict__ src, const int* __restrict__ dst,
                             const unsigned char* __restrict__ rank,
                             const int2* __restrict__ rowbounds, int* __restrict__ csr) {
    int i = (blockIdx.x * 256 + threadIdx.x) * 4;
    int4 s = *(const int4*)(src + i);
    int4 d = *(const int4*)(dst + i);
    uchar4 r = *(const uchar4*)(rank + i);
    const int* rs = (const int*)rowbounds;  // .x of int2 = row start
    csr[rs[2 * d.x] + r.x] = s.x << 6;  // byte off into 64B fp8 row | >>2: x16 bf16 row
    csr[rs[2 * d.y] + r.y] = s.y << 6;
    csr[rs[2 * d.z] + r.z] = s.z << 6;
    csr[rs[2 * d.w] + r.w] = s.w << 6;
}

// ---- layer-1 aggregation over prescaled x table: wave = 32 nodes ----
__global__ void agg_x_kernel(const int2* __restrict__ rowbounds, const int* __restrict__ csr,
                             const float* __restrict__ dinv,
                             const unsigned short* __restrict__ xb, float* __restrict__ aggx) {
    int tid = threadIdx.x;
    int w = tid >> 6, lane = tid & 63, sub = lane >> 1, p = lane & 1;
    int qoff = 8 * p;
    int node = (blockIdx.x * 4 + w) * 32 + sub;
    int2 rb = rowbounds[node];
    float dn = dinv[node];
    f32x2 a0[4] = {{0, 0}, {0, 0}, {0, 0}, {0, 0}};
    f32x2 a1[4] = {{0, 0}, {0, 0}, {0, 0}, {0, 0}};
    f32x2 a2[4] = {{0, 0}, {0, 0}, {0, 0}, {0, 0}};
    f32x2 a3[4] = {{0, 0}, {0, 0}, {0, 0}, {0, 0}};
    for (int j = rb.x; j < rb.y; j += 4) {  // padded x4: no remainder
        int4 e = *(const int4*)(csr + j);
        uint4 u0 = *(const uint4*)(xb + (e.x >> 2) + qoff);
        uint4 u1 = *(const uint4*)(xb + (e.y >> 2) + qoff);
        uint4 u2 = *(const uint4*)(xb + (e.z >> 2) + qoff);
        uint4 u3 = *(const uint4*)(xb + (e.w >> 2) + qoff);
        a0[0] += (f32x2){bflo(u0.x), bfhi(u0.x)};
        a0[1] += (f32x2){bflo(u0.y), bfhi(u0.y)};
        a0[2] += (f32x2){bflo(u0.z), bfhi(u0.z)};
        a0[3] += (f32x2){bflo(u0.w), bfhi(u0.w)};
        a1[0] += (f32x2){bflo(u1.x), bfhi(u1.x)};
        a1[1] += (f32x2){bflo(u1.y), bfhi(u1.y)};
        a1[2] += (f32x2){bflo(u1.z), bfhi(u1.z)};
        a1[3] += (f32x2){bflo(u1.w), bfhi(u1.w)};
        a2[0] += (f32x2){bflo(u2.x), bfhi(u2.x)};
        a2[1] += (f32x2){bflo(u2.y), bfhi(u2.y)};
        a2[2] += (f32x2){bflo(u2.z), bfhi(u2.z)};
        a2[3] += (f32x2){bflo(u2.w), bfhi(u2.w)};
        a3[0] += (f32x2){bflo(u3.x), bfhi(u3.x)};
        a3[1] += (f32x2){bflo(u3.y), bfhi(u3.y)};
        a3[2] += (f32x2){bflo(u3.z), bfhi(u3.z)};
        a3[3] += (f32x2){bflo(u3.w), bfhi(u3.w)};
    }
    uint4 su = *(const uint4*)(xb + node * 16 + qoff);  // xb' already has dinv_s
    a0[0] += (f32x2){bflo(su.x), bfhi(su.x)};
    a0[1] += (f32x2){bflo(su.y), bfhi(su.y)};
    a0[2] += (f32x2){bflo(su.z), bfhi(su.z)};
    a0[3] += (f32x2){bflo(su.w), bfhi(su.w)};
    f32x2 nd = {dn, dn};
    f32x2 s0 = nd * ((a0[0] + a1[0]) + (a2[0] + a3[0]));
    f32x2 s1 = nd * ((a0[1] + a1[1]) + (a2[1] + a3[1]));
    f32x2 s2 = nd * ((a0[2] + a1[2]) + (a2[2] + a3[2]));
    f32x2 s3 = nd * ((a0[3] + a1[3]) + (a2[3] + a3[3]));
    float4 o0 = make_float4(s0[0], s0[1], s1[0], s1[1]);
    float4 o1 = make_float4(s2[0], s2[1], s3[0], s3[1]);
    *(float4*)(aggx + node * 16 + qoff) = o0;
    *(float4*)(aggx + node * 16 + qoff + 4) = o1;
}

// ---- fused w1+w2, register-tiled: 64 nodes/block; h1 transposed in LDS ----
__global__ void w1w2_kernel(const float* __restrict__ aggx, const float* __restrict__ W1,
                            const float* __restrict__ b1, const float* __restrict__ W2,
                            const float* __restrict__ dinv, unsigned int* __restrict__ hout) {
    __shared__ float sW1[IN_CH * HID];     // 3 KB
    __shared__ float sW2[HID * HID];       // 16 KB
    __shared__ float sA[64 * 17];          // 4.25 KB (padded pitch 17)
    __shared__ float sh1t[HID * 65];       // 16.25 KB: h1^T [ch][node], pitch 65
    int tid = threadIdx.x;
    for (int i = tid; i < IN_CH * HID; i += 256) sW1[i] = W1[i];
    for (int i = tid; i < HID * HID; i += 256) sW2[i] = W2[i];
    int node0 = blockIdx.x * 64;
    {   // load 64 aggx rows (16 fp32 each), store padded
        float4 v = *(const float4*)(aggx + node0 * 16 + tid * 4);
        int n = tid >> 2, part = (tid & 3) * 4;
        sA[n * 17 + part + 0] = v.x;
        sA[n * 17 + part + 1] = v.y;
        sA[n * 17 + part + 2] = v.z;
        sA[n * 17 + part + 3] = v.w;
    }
    __syncthreads();
    // phase 1 (W1): wave w computes 16-node x 64-ch tile; lane = channel
    int w = tid >> 6, c = tid & 63;
    float bc = b1[c];
#pragma unroll
    for (int it = 0; it < 4; it++) {
        int n0 = w * 16 + it * 4;
        float a0 = bc, a1 = bc, a2 = bc, a3 = bc;
#pragma unroll
        for (int k = 0; k < IN_CH; k++) {
            float wv = sW1[k * HID + c];
            a0 += sA[(n0 + 0) * 17 + k] * wv;  // sA reads broadcast per wave
            a1 += sA[(n0 + 1) * 17 + k] * wv;
            a2 += sA[(n0 + 2) * 17 + k] * wv;
            a3 += sA[(n0 + 3) * 17 + k] * wv;
        }
        float4 o = make_float4(fmaxf(a0, 0.0f), fmaxf(a1, 0.0f),
                               fmaxf(a2, 0.0f), fmaxf(a3, 0.0f));
        *(float4*)&sh1t[c * 65 + n0] = o;  // transposed: [ch][node]
    }
    __syncthreads();
    // phase 2 (W2): thread = 4 nodes x 4 ch; per k: 2 x b128 for 16 FMA
    int nq = tid >> 4, c4 = (tid & 15) * 4;
    float4 a0 = {0, 0, 0, 0}, a1 = {0, 0, 0, 0}, a2 = {0, 0, 0, 0}, a3 = {0, 0, 0, 0};
#pragma unroll 4
    for (int k = 0; k < HID; k++) {
        float4 wv = *(const float4*)&sW2[k * HID + c4];
        float4 hv = *(const float4*)&sh1t[k * 65 + nq * 4];  // 4 nodes' h1[k]
        a0.x += hv.x * wv.x; a0.y += hv.x * wv.y; a0.z += hv.x * wv.z; a0.w += hv.x * wv.w;
        a1.x += hv.y * wv.x; a1.y += hv.y * wv.y; a1.z += hv.y * wv.z; a1.w += hv.y * wv.w;
        a2.x += hv.z * wv.x; a2.y += hv.z * wv.y; a2.z += hv.z * wv.z; a2.w += hv.z * wv.w;
        a3.x += hv.w * wv.x; a3.y += hv.w * wv.y; a3.z += hv.w * wv.z; a3.w += hv.w * wv.w;
    }
    int nb = node0 + nq * 4;
    float dv0 = dinv[nb + 0], dv1 = dinv[nb + 1], dv2 = dinv[nb + 2], dv3 = dinv[nb + 3];
    unsigned int p0 = (unsigned int)__builtin_amdgcn_cvt_pk_fp8_f32(dv0 * a0.x, dv0 * a0.y, 0, false);
    p0 = (unsigned int)__builtin_amdgcn_cvt_pk_fp8_f32(dv0 * a0.z, dv0 * a0.w, (int)p0, true);
    unsigned int p1 = (unsigned int)__builtin_amdgcn_cvt_pk_fp8_f32(dv1 * a1.x, dv1 * a1.y, 0, false);
    p1 = (unsigned int)__builtin_amdgcn_cvt_pk_fp8_f32(dv1 * a1.z, dv1 * a1.w, (int)p1, true);
    unsigned int p2 = (unsigned int)__builtin_amdgcn_cvt_pk_fp8_f32(dv2 * a2.x, dv2 * a2.y, 0, false);
    p2 = (unsigned int)__builtin_amdgcn_cvt_pk_fp8_f32(dv2 * a2.z, dv2 * a2.w, (int)p2, true);
    unsigned int p3 = (unsigned int)__builtin_amdgcn_cvt_pk_fp8_f32(dv3 * a3.x, dv3 * a3.y, 0, false);
    p3 = (unsigned int)__builtin_amdgcn_cvt_pk_fp8_f32(dv3 * a3.z, dv3 * a3.w, (int)p3, true);
    int cl = c4 >> 2;
    hout[(nb + 0) * 16 + cl] = p0;   // per-instruction: 64B runs, fully coalesced
    hout[(nb + 1) * 16 + cl] = p1;
    hout[(nb + 2) * 16 + cl] = p2;
    hout[(nb + 3) * 16 + cl] = p3;
    if (blockIdx.x == 0 && tid < 16)  // zero row N_NODES (pad target)
        hout[(size_t)N_NODES * 16 + tid] = 0;
}

// ---- layer-2 fp8 gather body: no per-edge norm; 8 edges in flight ----
__device__ __forceinline__ void add_fp8(f32x2* a, uint2 u) {
    a[0] += __builtin_amdgcn_cvt_pk_f32_fp8((int)u.x, false);
    a[1] += __builtin_amdgcn_cvt_pk_f32_fp8((int)u.x, true);
    a[2] += __builtin_amdgcn_cvt_pk_f32_fp8((int)u.y, false);
    a[3] += __builtin_amdgcn_cvt_pk_f32_fp8((int)u.y, true);
}

__device__ __forceinline__ void agg_body(int beg, int end, const int* __restrict__ csr,
                                         const unsigned char* __restrict__ h,
                                         int qoff, float* r) {
    f32x2 a0[4] = {{0, 0}, {0, 0}, {0, 0}, {0, 0}};
    f32x2 a1[4] = {{0, 0}, {0, 0}, {0, 0}, {0, 0}};
    f32x2 a2[4] = {{0, 0}, {0, 0}, {0, 0}, {0, 0}};
    f32x2 a3[4] = {{0, 0}, {0, 0}, {0, 0}, {0, 0}};
    int j = beg;
    for (; j + 8 <= end; j += 8) {  // 8 edges in flight
        int4 ea = *(const int4*)(csr + j);
        int4 eb = *(const int4*)(csr + j + 4);
        uint2 u0 = *(const uint2*)(h + ea.x + qoff);
        uint2 u1 = *(const uint2*)(h + ea.y + qoff);
        uint2 u2 = *(const uint2*)(h + ea.z + qoff);
        uint2 u3 = *(const uint2*)(h + ea.w + qoff);
        uint2 u4 = *(const uint2*)(h + eb.x + qoff);
        uint2 u5 = *(const uint2*)(h + eb.y + qoff);
        uint2 u6 = *(const uint2*)(h + eb.z + qoff);
        uint2 u7 = *(const uint2*)(h + eb.w + qoff);
        add_fp8(a0, u0); add_fp8(a1, u1); add_fp8(a2, u2); add_fp8(a3, u3);
        add_fp8(a0, u4); add_fp8(a1, u5); add_fp8(a2, u6); add_fp8(a3, u7);
    }
    if (j < end) {  // exactly 4 padded edges remain
        int4 ea = *(const int4*)(csr + j);
        uint2 u0 = *(const uint2*)(h + ea.x + qoff);
        uint2 u1 = *(const uint2*)(h + ea.y + qoff);
        uint2 u2 = *(const uint2*)(h + ea.z + qoff);
        uint2 u3 = *(const uint2*)(h + ea.w + qoff);
        add_fp8(a0, u0); add_fp8(a1, u1); add_fp8(a2, u2); add_fp8(a3, u3);
    }
#pragma unroll
    for (int k = 0; k < 4; k++) {
        f32x2 s = (a0[k] + a1[k]) + (a2[k] + a3[k]);
        r[2 * k] = s[0];
        r[2 * k + 1] = s[1];
    }
}

// ---- layer-2 gather-aggregate + relu + fused mean-pool (run-length flush) ----
__global__ void agg_pool_kernel(const int2* __restrict__ rowbounds, const int* __restrict__ csr,
                                const float* __restrict__ dinv,
                                const unsigned char* __restrict__ h,
                                const float* __restrict__ b, const int* __restrict__ batch,
                                float* __restrict__ pool, float* __restrict__ gcnt) {
    __shared__ float red[32][HID];  // 8 KB
    __shared__ int gids[32];
    int tid = threadIdx.x;
    int w = tid >> 6, lane = tid & 63, sub = lane >> 3, q = lane & 7;
    int qoff = 8 * q;
    int node = (blockIdx.x * 4 + w) * 8 + sub;
    int2 rb = rowbounds[node];
    float dn = dinv[node];
    float r[8];
    agg_body(rb.x, rb.y, csr, h, qoff, r);
    uint2 su = *(const uint2*)(h + node * HID + qoff);  // hB' already has dinv_s
    f32x2 s0 = __builtin_amdgcn_cvt_pk_f32_fp8((int)su.x, false);
    f32x2 s1 = __builtin_amdgcn_cvt_pk_f32_fp8((int)su.x, true);
    f32x2 s2 = __builtin_amdgcn_cvt_pk_f32_fp8((int)su.y, false);
    f32x2 s3 = __builtin_amdgcn_cvt_pk_f32_fp8((int)su.y, true);
    float4 b0 = *(const float4*)&b[qoff];
    float4 b1 = *(const float4*)&b[qoff + 4];
    float4 v0, v1;
    v0.x = fmaxf(dn * (r[0] + s0[0]) + b0.x, 0.0f);
    v0.y = fmaxf(dn * (r[1] + s0[1]) + b0.y, 0.0f);
    v0.z = fmaxf(dn * (r[2] + s1[0]) + b0.z, 0.0f);
    v0.w = fmaxf(dn * (r[3] + s1[1]) + b0.w, 0.0f);
    v1.x = fmaxf(dn * (r[4] + s2[0]) + b1.x, 0.0f);
    v1.y = fmaxf(dn * (r[5] + s2[1]) + b1.y, 0.0f);
    v1.z = fmaxf(dn * (r[6] + s3[0]) + b1.z, 0.0f);
    v1.w = fmaxf(dn * (r[7] + s3[1]) + b1.w, 0.0f);
    int nl = w * 8 + sub;
    *(float4*)&red[nl][qoff] = v0;
    *(float4*)&red[nl][qoff + 4] = v1;
    if (q == 0) gids[nl] = batch[node];
    __syncthreads();
    if (tid < 64) {  // wave 0: run-length reduce 32 nodes (batch sorted)
        int c = tid;
        float acc = 0.0f;
        int cur = gids[0], cnt = 0;
        for (int n = 0; n < 32; n++) {
            int g = gids[n];
            if (g != cur) {
                atomicAdd(&pool[cur * HID + c], acc);
                if (c == 0) atomicAdd(&gcnt[cur], (float)cnt);
                acc = 0.0f; cnt = 0; cur = g;
            }
            acc += red[n][c];
            cnt++;
        }
        atomicAdd(&pool[cur * HID + c], acc);
        if (c == 0) atomicAdd(&gcnt[cur], (float)cnt);
    }
}

// ---- final: out = sigmoid((pool/cnt) @ Wfc + bfc) ----
__global__ void final_kernel(const float* __restrict__ pool, const float* __restrict__ gcnt,
                             const float* __restrict__ Wfc, const float* __restrict__ bfc,
                             float* __restrict__ out) {
    int idx = blockIdx.x * 256 + threadIdx.x;
    if (idx >= N_GRAPHS * OUT_CH) return;
    int g = idx >> 2, o = idx & 3;
    float inv = 1.0f / fmaxf(gcnt[g], 1.0f);
    float acc = bfc[o];
#pragma unroll
    for (int k = 0; k < HID; k++) acc += pool[g * HID + k] * inv * Wfc[k * OUT_CH + o];
    out[idx] = 1.0f / (1.0f + expf(-acc));
}

extern "C" void kernel_launch(void* const* d_in, const int* in_sizes, int n_in,
                              void* d_out, int out_size, void* d_ws, size_t ws_size,
                              hipStream_t stream) {
    const float* x   = (const float*)d_in[0];
    const int* eidx  = (const int*)d_in[1];
    const int* batch = (const int*)d_in[2];
    const float* W1  = (const float*)d_in[3];
    const float* b1  = (const float*)d_in[4];
    const float* W2  = (const float*)d_in[5];
    const float* b2  = (const float*)d_in[6];
    const float* Wfc = (const float*)d_in[7];
    const float* bfc = (const float*)d_in[8];
    float* out = (float*)d_out;

    const int* src = eidx;
    const int* dst = eidx + N_EDGES;

    // workspace layout (~37 MB)
    unsigned char* hB = (unsigned char*)d_ws;                   // 8.4 MB fp8 (+1 zero row)
    int*   csr  = (int*)(hB + (size_t)(N_NODES + 1) * HID);     // 10.24 MB src<<6, compact
    float* dinv = (float*)(csr + CSR_CAP);                      // 512 KB
    int2*  rowbounds = (int2*)(dinv + N_NODES);                 // 1 MB
    unsigned short* xb = (unsigned short*)(rowbounds + N_NODES); // 4 MB bf16 [N+1,16]
    float* aggx = (float*)(xb + (size_t)(N_NODES + 1) * 16);    // 8 MB fp32 [N,16]
    unsigned char* rank = (unsigned char*)(aggx + (size_t)N_NODES * 16); // 2 MB
    // zeroed block (single memset): deg | pool | gcnt | gcur
    int*   deg  = (int*)(rank + N_EDGES);                       // 512 KB
    float* pool = (float*)(deg + N_NODES);                      // 512 KB
    float* gcnt = pool + N_GRAPHS * HID;                        // 8 KB
    int*   gcur = (int*)(gcnt + N_GRAPHS);                      // 16 B

    hipMemsetAsync(deg, 0, (size_t)(N_NODES + N_GRAPHS * HID + N_GRAPHS + 4) * 4, stream);

    // CSR build: count(+rank) -> order-free reserve (+prescaled xcast) -> atomic-free place
    count_kernel<<<N_EDGES / 1024, 256, 0, stream>>>(dst, deg, rank);
    reserve_kernel<<<N_NODES / 256, 256, 0, stream>>>(deg, gcur, rowbounds, dinv, csr, x, xb);
    place_kernel<<<N_EDGES / 1024, 256, 0, stream>>>(src, dst, rank, rowbounds, csr);

    // layer 1: agg(x') then fused register-tiled W1+W2 (h1 LDS-only) -> fp8 hB'
    agg_x_kernel<<<N_NODES / 128, 256, 0, stream>>>(rowbounds, csr, dinv, xb, aggx);
    w1w2_kernel<<<N_NODES / 64, 256, 0, stream>>>(aggx, W1, b1, W2, dinv, (unsigned int*)hB);

    // layer 2: gather + pool
    agg_pool_kernel<<<N_NODES / 32, 256, 0, stream>>>(rowbounds, csr, dinv, hB, b2, batch,
                                                      pool, gcnt);

    // head
    final_kernel<<<(N_GRAPHS * OUT_CH + 255) / 256, 256, 0, stream>>>(pool, gcnt, Wfc, bfc, out);
}

// Round 2
// 185.730 us; speedup vs baseline: 1.5664x; 1.5664x over previous
//
#include <hip/hip_runtime.h>
#include <hip/hip_bf16.h>

// GCN. CSR via 2-pass LDS bucket sort (R1 lesson: global atomic count/rank writes
// through HBM at 850 GB/s -> 86us; LDS-bucketed build is ~15us. Keep it.)
// R2: (a) agg_x fused INTO w1w2 (deletes 8MB aggx round-trip + a launch): 4 thr/node
// = 2 edge-half pairs x 2 ch-halves, shfl_xor(2) combine, straight into sA.
// (b) agg_pool regathered as 4 thr/node x uint4 (halves gather instr count; red
// pitch +4 to avoid pitch-64 bank conflicts).
// Layer 2: single 8 MB fp8 table (R17: splitting doubles per-edge line requests).

#define N_NODES 131072
#define N_EDGES 2097152
#define N_GRAPHS 2048
#define IN_CH 12
#define HID 64
#define OUT_CH 4
#define NBUCK 512          // buckets of 256 dst nodes
#define CHUNK 8192         // edges per bucket_kernel block
#define STRIDE 4608        // staging capacity per bucket (mean 4096, sd 64)
#define CSR_STRIDE 5120    // csr capacity per bucket (padded mean ~4500)
#define CAP 5120           // build_kernel LDS image capacity (20.5 KB, int)

typedef float f32x2 __attribute__((ext_vector_type(2)));

__device__ __forceinline__ unsigned short f2bf(float f) {
    unsigned u = __float_as_uint(f);
    return (unsigned short)((u + 0x7fffu + ((u >> 16) & 1u)) >> 16);  // RNE
}
__device__ __forceinline__ unsigned pack2bf(float lo, float hi) {
    return (unsigned)f2bf(lo) | ((unsigned)f2bf(hi) << 16);
}
__device__ __forceinline__ float bflo(unsigned v) { return __uint_as_float(v << 16); }
__device__ __forceinline__ float bfhi(unsigned v) { return __uint_as_float(v & 0xFFFF0000u); }

// ---- pass A: LDS bucket sort of edges by dst>>8 into strided staging ----
__global__ __launch_bounds__(1024, 4)
void bucket_kernel(const int* __restrict__ src, const int* __restrict__ dst,
                   int* __restrict__ bucket_count, int* __restrict__ staged) {
    __shared__ int hist[NBUCK];
    __shared__ int lscan[NBUCK];
    __shared__ int gbase[NBUCK];
    __shared__ int cursor[NBUCK];
    __shared__ int sorted[CHUNK];  // 32 KB
    int tid = threadIdx.x;
    int base = blockIdx.x * CHUNK;
    if (tid < NBUCK) { hist[tid] = 0; cursor[tid] = 0; }
    __syncthreads();
    int d8[8], s8[8];
#pragma unroll
    for (int k = 0; k < 8; k++) {
        int i = base + k * 1024 + tid;
        d8[k] = dst[i];
        s8[k] = src[i];
        atomicAdd(&hist[d8[k] >> 8], 1);
    }
    __syncthreads();
    if (tid < NBUCK) lscan[tid] = hist[tid];
    __syncthreads();
    for (int off = 1; off < NBUCK; off <<= 1) {
        int u = (tid < NBUCK && tid >= off) ? lscan[tid - off] : 0;
        __syncthreads();
        if (tid < NBUCK) lscan[tid] += u;
        __syncthreads();
    }
    if (tid < NBUCK) gbase[tid] = atomicAdd(&bucket_count[tid], hist[tid]);
    __syncthreads();
#pragma unroll
    for (int k = 0; k < 8; k++) {
        int b = d8[k] >> 8;
        int start = lscan[b] - hist[b];
        int p = start + atomicAdd(&cursor[b], 1);
        sorted[p] = ((d8[k] & 255) << 17) | s8[k];
    }
    __syncthreads();
    int wid = tid >> 6, lane = tid & 63;
    int g16 = lane >> 4, k16 = lane & 15;
    for (int b0 = wid * 4; b0 < NBUCK; b0 += 64) {
        int b = b0 + g16;
        int cb = hist[b];
        int lbase = lscan[b] - cb;
        int gb = b * STRIDE + gbase[b];
        for (int k = k16; k < cb; k += 16) staged[gb + k] = sorted[lbase + k];
    }
}

// ---- per-bucket: count + scan + place in one kernel; + prescaled x cast ----
__global__ void build_kernel(const int* __restrict__ bucket_count, const int* __restrict__ staged,
                             int2* __restrict__ rowbounds, float* __restrict__ dinv,
                             int* __restrict__ csr, const float* __restrict__ x,
                             unsigned short* __restrict__ xb) {
    __shared__ int sl[STRIDE];     // 18.4 KB bucket slice
    __shared__ int image[CAP];     // 20.5 KB csr image (src<<6)
    __shared__ int cnt[256];
    __shared__ int scn[256];
    __shared__ int loff[256];
    __shared__ int cursor[256];
    __shared__ int totalS;
    int b = blockIdx.x;
    int tid = threadIdx.x;
    int count = bucket_count[b];
    const int* st = staged + b * STRIDE;
    cnt[tid] = 0;
    cursor[tid] = 0;
    for (int i = tid; i < count; i += 256) sl[i] = st[i];
    __syncthreads();
    for (int i = tid; i < count; i += 256) atomicAdd(&cnt[(sl[i] >> 17) & 255], 1);
    __syncthreads();
    int deg = cnt[tid];
    int degp = (deg + 3) & ~3;  // pad to x4
    scn[tid] = degp;
    __syncthreads();
    for (int off = 1; off < 256; off <<= 1) {
        int u = (tid >= off) ? scn[tid - off] : 0;
        __syncthreads();
        scn[tid] += u;
        __syncthreads();
    }
    int lo = scn[tid] - degp;
    loff[tid] = lo;
    int nbase = (b << 8) + tid;
    int gb = b * CSR_STRIDE;
    rowbounds[nbase] = make_int2(gb + lo, gb + lo + degp);
    float dv = rsqrtf((float)deg + 1.0f);
    dinv[nbase] = dv;
    if (tid == 255) totalS = lo + degp;
    {
        const float* xp = x + nbase * IN_CH;
        unsigned o[8];
#pragma unroll
        for (int k = 0; k < 6; k++) o[k] = pack2bf(dv * xp[2 * k], dv * xp[2 * k + 1]);
        o[6] = 0; o[7] = 0;
        uint4* dstp = (uint4*)(xb + nbase * 16);
        dstp[0] = make_uint4(o[0], o[1], o[2], o[3]);
        dstp[1] = make_uint4(o[4], o[5], o[6], o[7]);
    }
    if (b == 0 && tid < 2)  // zero row N_NODES of xb (pad target)
        ((uint4*)(xb + (size_t)N_NODES * 16))[tid] = make_uint4(0, 0, 0, 0);
    __syncthreads();
    for (int i = tid; i < count; i += 256) {
        int rec = sl[i];
        int s = rec & 0x1FFFF;
        int dq = (rec >> 17) & 255;
        int p = loff[dq] + atomicAdd(&cursor[dq], 1);
        int val = s << 6;  // byte off into 64B fp8 row | >>2: x16 bf16 row
        if (p < CAP) image[p] = val;
        else csr[gb + p] = val;
    }
    __syncthreads();
    int padval = N_NODES << 6;  // zero row
    for (int p = loff[tid] + deg; p < loff[tid] + degp; p++) {
        if (p < CAP) image[p] = padval;
        else csr[gb + p] = padval;
    }
    __syncthreads();
    int lim = totalS < CAP ? totalS : CAP;
    int* dstp = csr + gb;
    for (int i = tid; i < lim; i += 256) dstp[i] = image[i];
}

// ---- fused layer-1 gather + w1 + w2, register-tiled: 64 nodes/block ----
__global__ void w1w2_kernel(const int2* __restrict__ rowbounds, const int* __restrict__ csr,
                            const float* __restrict__ dinv, const unsigned short* __restrict__ xb,
                            const float* __restrict__ W1, const float* __restrict__ b1,
                            const float* __restrict__ W2, unsigned int* __restrict__ hout) {
    __shared__ float sW1[IN_CH * HID];     // 3 KB
    __shared__ float sW2[HID * HID];       // 16 KB
    __shared__ float sA[64 * 17];          // 4.25 KB (padded pitch 17)
    __shared__ float sh1t[HID * 65];       // 16.25 KB: h1^T [ch][node], pitch 65
    int tid = threadIdx.x;
    for (int i = tid; i < IN_CH * HID; i += 256) sW1[i] = W1[i];
    for (int i = tid; i < HID * HID; i += 256) sW2[i] = W2[i];
    int node0 = blockIdx.x * 64;
    {   // gather phase: 4 thr/node = 2 edge-halves x 2 ch-halves; weight loads overlap
        int nl = tid >> 2;
        int node = node0 + nl;
        int p = tid & 1, qoff = 8 * p;  // shorts
        int2 rb = rowbounds[node];
        int len = rb.y - rb.x;
        int hlen = (len >> 3) << 2;     // first half, mult of 4
        int beg = (tid & 2) ? rb.x + hlen : rb.x;
        int end = (tid & 2) ? rb.y : rb.x + hlen;
        f32x2 a0[4] = {{0, 0}, {0, 0}, {0, 0}, {0, 0}};
        f32x2 a1[4] = {{0, 0}, {0, 0}, {0, 0}, {0, 0}};
        f32x2 a2[4] = {{0, 0}, {0, 0}, {0, 0}, {0, 0}};
        f32x2 a3[4] = {{0, 0}, {0, 0}, {0, 0}, {0, 0}};
        for (int j = beg; j < end; j += 4) {  // padded x4: no remainder
            int4 e = *(const int4*)(csr + j);
            uint4 u0 = *(const uint4*)(xb + (e.x >> 2) + qoff);
            uint4 u1 = *(const uint4*)(xb + (e.y >> 2) + qoff);
            uint4 u2 = *(const uint4*)(xb + (e.z >> 2) + qoff);
            uint4 u3 = *(const uint4*)(xb + (e.w >> 2) + qoff);
            a0[0] += (f32x2){bflo(u0.x), bfhi(u0.x)};
            a0[1] += (f32x2){bflo(u0.y), bfhi(u0.y)};
            a0[2] += (f32x2){bflo(u0.z), bfhi(u0.z)};
            a0[3] += (f32x2){bflo(u0.w), bfhi(u0.w)};
            a1[0] += (f32x2){bflo(u1.x), bfhi(u1.x)};
            a1[1] += (f32x2){bflo(u1.y), bfhi(u1.y)};
            a1[2] += (f32x2){bflo(u1.z), bfhi(u1.z)};
            a1[3] += (f32x2){bflo(u1.w), bfhi(u1.w)};
            a2[0] += (f32x2){bflo(u2.x), bfhi(u2.x)};
            a2[1] += (f32x2){bflo(u2.y), bfhi(u2.y)};
            a2[2] += (f32x2){bflo(u2.z), bfhi(u2.z)};
            a2[3] += (f32x2){bflo(u2.w), bfhi(u2.w)};
            a3[0] += (f32x2){bflo(u3.x), bfhi(u3.x)};
            a3[1] += (f32x2){bflo(u3.y), bfhi(u3.y)};
            a3[2] += (f32x2){bflo(u3.z), bfhi(u3.z)};
            a3[3] += (f32x2){bflo(u3.w), bfhi(u3.w)};
        }
        f32x2 s0 = (a0[0] + a1[0]) + (a2[0] + a3[0]);
        f32x2 s1 = (a0[1] + a1[1]) + (a2[1] + a3[1]);
        f32x2 s2 = (a0[2] + a1[2]) + (a2[2] + a3[2]);
        f32x2 s3 = (a0[3] + a1[3]) + (a2[3] + a3[3]);
        s0[0] += __shfl_xor(s0[0], 2); s0[1] += __shfl_xor(s0[1], 2);
        s1[0] += __shfl_xor(s1[0], 2); s1[1] += __shfl_xor(s1[1], 2);
        s2[0] += __shfl_xor(s2[0], 2); s2[1] += __shfl_xor(s2[1], 2);
        s3[0] += __shfl_xor(s3[0], 2); s3[1] += __shfl_xor(s3[1], 2);
        if (!(tid & 2)) {
            uint4 su = *(const uint4*)(xb + node * 16 + qoff);  // xb' already has dinv_s
            s0 += (f32x2){bflo(su.x), bfhi(su.x)};
            s1 += (f32x2){bflo(su.y), bfhi(su.y)};
            s2 += (f32x2){bflo(su.z), bfhi(su.z)};
            s3 += (f32x2){bflo(su.w), bfhi(su.w)};
            float dn = dinv[node];
            float* dp = &sA[nl * 17 + qoff];
            dp[0] = dn * s0[0]; dp[1] = dn * s0[1];
            dp[2] = dn * s1[0]; dp[3] = dn * s1[1];
            dp[4] = dn * s2[0]; dp[5] = dn * s2[1];
            dp[6] = dn * s3[0]; dp[7] = dn * s3[1];
        }
    }
    __syncthreads();
    // phase 1 (W1): wave w computes 16-node x 64-ch tile; lane = channel
    int w = tid >> 6, c = tid & 63;
    float bc = b1[c];
#pragma unroll
    for (int it = 0; it < 4; it++) {
        int n0 = w * 16 + it * 4;
        float a0 = bc, a1 = bc, a2 = bc, a3 = bc;
#pragma unroll
        for (int k = 0; k < IN_CH; k++) {
            float wv = sW1[k * HID + c];
            a0 += sA[(n0 + 0) * 17 + k] * wv;  // sA reads broadcast per wave
            a1 += sA[(n0 + 1) * 17 + k] * wv;
            a2 += sA[(n0 + 2) * 17 + k] * wv;
            a3 += sA[(n0 + 3) * 17 + k] * wv;
        }
        float4 o = make_float4(fmaxf(a0, 0.0f), fmaxf(a1, 0.0f),
                               fmaxf(a2, 0.0f), fmaxf(a3, 0.0f));
        *(float4*)&sh1t[c * 65 + n0] = o;  // transposed: [ch][node]
    }
    __syncthreads();
    // phase 2 (W2): thread = 4 nodes x 4 ch; per k: 2 x b128 for 16 FMA
    int nq = tid >> 4, c4 = (tid & 15) * 4;
    float4 a0 = {0, 0, 0, 0}, a1 = {0, 0, 0, 0}, a2 = {0, 0, 0, 0}, a3 = {0, 0, 0, 0};
#pragma unroll 4
    for (int k = 0; k < HID; k++) {
        float4 wv = *(const float4*)&sW2[k * HID + c4];
        float4 hv = *(const float4*)&sh1t[k * 65 + nq * 4];  // 4 nodes' h1[k]
        a0.x += hv.x * wv.x; a0.y += hv.x * wv.y; a0.z += hv.x * wv.z; a0.w += hv.x * wv.w;
        a1.x += hv.y * wv.x; a1.y += hv.y * wv.y; a1.z += hv.y * wv.z; a1.w += hv.y * wv.w;
        a2.x += hv.z * wv.x; a2.y += hv.z * wv.y; a2.z += hv.z * wv.z; a2.w += hv.z * wv.w;
        a3.x += hv.w * wv.x; a3.y += hv.w * wv.y; a3.z += hv.w * wv.z; a3.w += hv.w * wv.w;
    }
    int nb = node0 + nq * 4;
    float dv0 = dinv[nb + 0], dv1 = dinv[nb + 1], dv2 = dinv[nb + 2], dv3 = dinv[nb + 3];
    unsigned int p0 = (unsigned int)__builtin_amdgcn_cvt_pk_fp8_f32(dv0 * a0.x, dv0 * a0.y, 0, false);
    p0 = (unsigned int)__builtin_amdgcn_cvt_pk_fp8_f32(dv0 * a0.z, dv0 * a0.w, (int)p0, true);
    unsigned int p1 = (unsigned int)__builtin_amdgcn_cvt_pk_fp8_f32(dv1 * a1.x, dv1 * a1.y, 0, false);
    p1 = (unsigned int)__builtin_amdgcn_cvt_pk_fp8_f32(dv1 * a1.z, dv1 * a1.w, (int)p1, true);
    unsigned int p2 = (unsigned int)__builtin_amdgcn_cvt_pk_fp8_f32(dv2 * a2.x, dv2 * a2.y, 0, false);
    p2 = (unsigned int)__builtin_amdgcn_cvt_pk_fp8_f32(dv2 * a2.z, dv2 * a2.w, (int)p2, true);
    unsigned int p3 = (unsigned int)__builtin_amdgcn_cvt_pk_fp8_f32(dv3 * a3.x, dv3 * a3.y, 0, false);
    p3 = (unsigned int)__builtin_amdgcn_cvt_pk_fp8_f32(dv3 * a3.z, dv3 * a3.w, (int)p3, true);
    int cl = c4 >> 2;
    hout[(nb + 0) * 16 + cl] = p0;   // per-instruction: 64B runs, fully coalesced
    hout[(nb + 1) * 16 + cl] = p1;
    hout[(nb + 2) * 16 + cl] = p2;
    hout[(nb + 3) * 16 + cl] = p3;
    if (blockIdx.x == 0 && tid < 16)  // zero row N_NODES (pad target)
        hout[(size_t)N_NODES * 16 + tid] = 0;
}

// ---- layer-2 fp8 gather body: 4 thr/node, uint4 (16 ch); 8 edges in flight ----
__device__ __forceinline__ void add_fp8q(f32x2* a, uint4 u) {
    a[0] += __builtin_amdgcn_cvt_pk_f32_fp8((int)u.x, false);
    a[1] += __builtin_amdgcn_cvt_pk_f32_fp8((int)u.x, true);
    a[2] += __builtin_amdgcn_cvt_pk_f32_fp8((int)u.y, false);
    a[3] += __builtin_amdgcn_cvt_pk_f32_fp8((int)u.y, true);
    a[4] += __builtin_amdgcn_cvt_pk_f32_fp8((int)u.z, false);
    a[5] += __builtin_amdgcn_cvt_pk_f32_fp8((int)u.z, true);
    a[6] += __builtin_amdgcn_cvt_pk_f32_fp8((int)u.w, false);
    a[7] += __builtin_amdgcn_cvt_pk_f32_fp8((int)u.w, true);
}

__device__ __forceinline__ void agg_body16(int beg, int end, const int* __restrict__ csr,
                                           const unsigned char* __restrict__ h,
                                           int qoff, float* r) {
    f32x2 a0[8] = {{0, 0}, {0, 0}, {0, 0}, {0, 0}, {0, 0}, {0, 0}, {0, 0}, {0, 0}};
    f32x2 a1[8] = {{0, 0}, {0, 0}, {0, 0}, {0, 0}, {0, 0}, {0, 0}, {0, 0}, {0, 0}};
    int j = beg;
    for (; j + 8 <= end; j += 8) {  // 8 edges in flight
        int4 ea = *(const int4*)(csr + j);
        int4 eb = *(const int4*)(csr + j + 4);
        uint4 u0 = *(const uint4*)(h + ea.x + qoff);
        uint4 u1 = *(const uint4*)(h + ea.y + qoff);
        uint4 u2 = *(const uint4*)(h + ea.z + qoff);
        uint4 u3 = *(const uint4*)(h + ea.w + qoff);
        uint4 u4 = *(const uint4*)(h + eb.x + qoff);
        uint4 u5 = *(const uint4*)(h + eb.y + qoff);
        uint4 u6 = *(const uint4*)(h + eb.z + qoff);
        uint4 u7 = *(const uint4*)(h + eb.w + qoff);
        add_fp8q(a0, u0); add_fp8q(a1, u1); add_fp8q(a0, u2); add_fp8q(a1, u3);
        add_fp8q(a0, u4); add_fp8q(a1, u5); add_fp8q(a0, u6); add_fp8q(a1, u7);
    }
    if (j < end) {  // exactly 4 padded edges remain
        int4 ea = *(const int4*)(csr + j);
        uint4 u0 = *(const uint4*)(h + ea.x + qoff);
        uint4 u1 = *(const uint4*)(h + ea.y + qoff);
        uint4 u2 = *(const uint4*)(h + ea.z + qoff);
        uint4 u3 = *(const uint4*)(h + ea.w + qoff);
        add_fp8q(a0, u0); add_fp8q(a1, u1); add_fp8q(a0, u2); add_fp8q(a1, u3);
    }
#pragma unroll
    for (int k = 0; k < 8; k++) {
        f32x2 s = a0[k] + a1[k];
        r[2 * k] = s[0];
        r[2 * k + 1] = s[1];
    }
}

// ---- layer-2 gather-aggregate + relu + fused mean-pool (run-length flush) ----
__global__ void agg_pool_kernel(const int2* __restrict__ rowbounds, const int* __restrict__ csr,
                                const float* __restrict__ dinv,
                                const unsigned char* __restrict__ h,
                                const float* __restrict__ b, const int* __restrict__ batch,
                                float* __restrict__ pool, float* __restrict__ gcnt) {
    __shared__ float red[64][HID + 4];  // 17 KB, padded pitch kills bank conflicts
    __shared__ int gids[64];
    int tid = threadIdx.x;
    int w = tid >> 6, lane = tid & 63, sub = lane >> 2, q = lane & 3;
    int qoff = 16 * q;  // byte offset in 64B fp8 row == channel offset
    int node = (blockIdx.x * 4 + w) * 16 + sub;
    int2 rb = rowbounds[node];
    float dn = dinv[node];
    float r[16];
    agg_body16(rb.x, rb.y, csr, h, qoff, r);
    uint4 su = *(const uint4*)(h + node * HID + qoff);  // hB' already has dinv_s
    f32x2 s[8];
    s[0] = __builtin_amdgcn_cvt_pk_f32_fp8((int)su.x, false);
    s[1] = __builtin_amdgcn_cvt_pk_f32_fp8((int)su.x, true);
    s[2] = __builtin_amdgcn_cvt_pk_f32_fp8((int)su.y, false);
    s[3] = __builtin_amdgcn_cvt_pk_f32_fp8((int)su.y, true);
    s[4] = __builtin_amdgcn_cvt_pk_f32_fp8((int)su.z, false);
    s[5] = __builtin_amdgcn_cvt_pk_f32_fp8((int)su.z, true);
    s[6] = __builtin_amdgcn_cvt_pk_f32_fp8((int)su.w, false);
    s[7] = __builtin_amdgcn_cvt_pk_f32_fp8((int)su.w, true);
    int nl = w * 16 + sub;
    float* rp = &red[nl][qoff];
#pragma unroll
    for (int k = 0; k < 4; k++) {
        float4 bv = *(const float4*)&b[qoff + 4 * k];
        rp[4 * k + 0] = fmaxf(dn * (r[4 * k + 0] + s[2 * k][0]) + bv.x, 0.0f);
        rp[4 * k + 1] = fmaxf(dn * (r[4 * k + 1] + s[2 * k][1]) + bv.y, 0.0f);
        rp[4 * k + 2] = fmaxf(dn * (r[4 * k + 2] + s[2 * k + 1][0]) + bv.z, 0.0f);
        rp[4 * k + 3] = fmaxf(dn * (r[4 * k + 3] + s[2 * k + 1][1]) + bv.w, 0.0f);
    }
    if (q == 0) gids[nl] = batch[node];
    __syncthreads();
    if (tid < 64) {  // wave 0: run-length reduce 64 nodes (batch sorted)
        int c = tid;
        float acc = 0.0f;
        int cur = gids[0], cnt = 0;
        for (int n = 0; n < 64; n++) {
            int g = gids[n];
            if (g != cur) {
                atomicAdd(&pool[cur * HID + c], acc);
                if (c == 0) atomicAdd(&gcnt[cur], (float)cnt);
                acc = 0.0f; cnt = 0; cur = g;
            }
            acc += red[n][c];
            cnt++;
        }
        atomicAdd(&pool[cur * HID + c], acc);
        if (c == 0) atomicAdd(&gcnt[cur], (float)cnt);
    }
}

// ---- final: out = sigmoid((pool/cnt) @ Wfc + bfc) ----
__global__ void final_kernel(const float* __restrict__ pool, const float* __restrict__ gcnt,
                             const float* __restrict__ Wfc, const float* __restrict__ bfc,
                             float* __restrict__ out) {
    int idx = blockIdx.x * 256 + threadIdx.x;
    if (idx >= N_GRAPHS * OUT_CH) return;
    int g = idx >> 2, o = idx & 3;
    float inv = 1.0f / fmaxf(gcnt[g], 1.0f);
    float acc = bfc[o];
#pragma unroll
    for (int k = 0; k < HID; k++) acc += pool[g * HID + k] * inv * Wfc[k * OUT_CH + o];
    out[idx] = 1.0f / (1.0f + expf(-acc));
}

extern "C" void kernel_launch(void* const* d_in, const int* in_sizes, int n_in,
                              void* d_out, int out_size, void* d_ws, size_t ws_size,
                              hipStream_t stream) {
    const float* x   = (const float*)d_in[0];
    const int* eidx  = (const int*)d_in[1];
    const int* batch = (const int*)d_in[2];
    const float* W1  = (const float*)d_in[3];
    const float* b1  = (const float*)d_in[4];
    const float* W2  = (const float*)d_in[5];
    const float* b2  = (const float*)d_in[6];
    const float* Wfc = (const float*)d_in[7];
    const float* bfc = (const float*)d_in[8];
    float* out = (float*)d_out;

    const int* src = eidx;
    const int* dst = eidx + N_EDGES;

    // workspace layout (~37 MB)
    unsigned char* hB = (unsigned char*)d_ws;                 // 8.4 MB fp8 (+1 zero row)
    int*   csr    = (int*)(hB + (size_t)(N_NODES + 1) * HID); // 10.5 MB src<<6
    int*   staged = csr + (size_t)NBUCK * CSR_STRIDE;         // 9.4 MB bucket-strided
    float* dinv   = (float*)(staged + (size_t)NBUCK * STRIDE); // 512 KB
    int2*  rowbounds = (int2*)(dinv + N_NODES);               // 1 MB
    int*   bucket_count = (int*)(rowbounds + N_NODES);        // 2 KB
    float* pool   = (float*)(bucket_count + NBUCK);           // 512 KB
    float* gcnt   = pool + N_GRAPHS * HID;                    // 8 KB
    unsigned short* xb = (unsigned short*)(gcnt + N_GRAPHS);  // 4 MB bf16 [N+1,16]

    // single memset: bucket_count | pool | gcnt are contiguous
    hipMemsetAsync(bucket_count, 0,
                   (size_t)(NBUCK + N_GRAPHS * HID + N_GRAPHS) * 4, stream);

    // CSR build: bucket sort -> fused count/scan/place (+prescaled xcast)
    bucket_kernel<<<N_EDGES / CHUNK, 1024, 0, stream>>>(src, dst, bucket_count, staged);
    build_kernel<<<NBUCK, 256, 0, stream>>>(bucket_count, staged, rowbounds, dinv, csr, x, xb);

    // layer 1: fused gather + register-tiled W1+W2 (h1 LDS-only) -> fp8 hB'
    w1w2_kernel<<<N_NODES / 64, 256, 0, stream>>>(rowbounds, csr, dinv, xb, W1, b1, W2,
                                                  (unsigned int*)hB);

    // layer 2: gather + pool
    agg_pool_kernel<<<N_NODES / 64, 256, 0, stream>>>(rowbounds, csr, dinv, hB, b2, batch,
                                                      pool, gcnt);

    // head
    final_kernel<<<(N_GRAPHS * OUT_CH + 255) / 256, 256, 0, stream>>>(pool, gcnt, Wfc, bfc, out);
}

// Round 3
// 180.785 us; speedup vs baseline: 1.6093x; 1.0274x over previous
//
#include <hip/hip_runtime.h>
#include <hip/hip_bf16.h>

// GCN. CSR via 2-pass LDS bucket sort (R1 lesson: global atomic count/rank writes
// through HBM at 850 GB/s -> 86us; LDS-bucketed build is ~15us. Keep it.)
// R2: agg_x fused into w1w2; agg_pool 4thr/node uint4. 185.7us, w1w2=46.4us top.
// R3: w1w2 was latency-bound at Occupancy 31% (LDS 40KB -> 4 blocks/CU). Drop the
// 16KB sW2 LDS copy -- phase 2 reads W2 straight from global (L1/L2-resident,
// 256B/wave/iter, latency hidden by 4-node FMA ILP). LDS 40.4->23.5KB -> 6
// blocks/CU via __launch_bounds__(256,6). Self-loop/dinv loads hoisted early.
// Layer 2: single 8 MB fp8 table (R17: splitting doubles per-edge line requests).

#define N_NODES 131072
#define N_EDGES 2097152
#define N_GRAPHS 2048
#define IN_CH 12
#define HID 64
#define OUT_CH 4
#define NBUCK 512          // buckets of 256 dst nodes
#define CHUNK 8192         // edges per bucket_kernel block
#define STRIDE 4608        // staging capacity per bucket (mean 4096, sd 64)
#define CSR_STRIDE 5120    // csr capacity per bucket (padded mean ~4500)
#define CAP 5120           // build_kernel LDS image capacity (20.5 KB, int)

typedef float f32x2 __attribute__((ext_vector_type(2)));

__device__ __forceinline__ unsigned short f2bf(float f) {
    unsigned u = __float_as_uint(f);
    return (unsigned short)((u + 0x7fffu + ((u >> 16) & 1u)) >> 16);  // RNE
}
__device__ __forceinline__ unsigned pack2bf(float lo, float hi) {
    return (unsigned)f2bf(lo) | ((unsigned)f2bf(hi) << 16);
}
__device__ __forceinline__ float bflo(unsigned v) { return __uint_as_float(v << 16); }
__device__ __forceinline__ float bfhi(unsigned v) { return __uint_as_float(v & 0xFFFF0000u); }

// ---- pass A: LDS bucket sort of edges by dst>>8 into strided staging ----
__global__ __launch_bounds__(1024, 4)
void bucket_kernel(const int* __restrict__ src, const int* __restrict__ dst,
                   int* __restrict__ bucket_count, int* __restrict__ staged) {
    __shared__ int hist[NBUCK];
    __shared__ int lscan[NBUCK];
    __shared__ int gbase[NBUCK];
    __shared__ int cursor[NBUCK];
    __shared__ int sorted[CHUNK];  // 32 KB
    int tid = threadIdx.x;
    int base = blockIdx.x * CHUNK;
    if (tid < NBUCK) { hist[tid] = 0; cursor[tid] = 0; }
    __syncthreads();
    int d8[8], s8[8];
#pragma unroll
    for (int k = 0; k < 8; k++) {
        int i = base + k * 1024 + tid;
        d8[k] = dst[i];
        s8[k] = src[i];
        atomicAdd(&hist[d8[k] >> 8], 1);
    }
    __syncthreads();
    if (tid < NBUCK) lscan[tid] = hist[tid];
    __syncthreads();
    for (int off = 1; off < NBUCK; off <<= 1) {
        int u = (tid < NBUCK && tid >= off) ? lscan[tid - off] : 0;
        __syncthreads();
        if (tid < NBUCK) lscan[tid] += u;
        __syncthreads();
    }
    if (tid < NBUCK) gbase[tid] = atomicAdd(&bucket_count[tid], hist[tid]);
    __syncthreads();
#pragma unroll
    for (int k = 0; k < 8; k++) {
        int b = d8[k] >> 8;
        int start = lscan[b] - hist[b];
        int p = start + atomicAdd(&cursor[b], 1);
        sorted[p] = ((d8[k] & 255) << 17) | s8[k];
    }
    __syncthreads();
    int wid = tid >> 6, lane = tid & 63;
    int g16 = lane >> 4, k16 = lane & 15;
    for (int b0 = wid * 4; b0 < NBUCK; b0 += 64) {
        int b = b0 + g16;
        int cb = hist[b];
        int lbase = lscan[b] - cb;
        int gb = b * STRIDE + gbase[b];
        for (int k = k16; k < cb; k += 16) staged[gb + k] = sorted[lbase + k];
    }
}

// ---- per-bucket: count + scan + place in one kernel; + prescaled x cast ----
__global__ void build_kernel(const int* __restrict__ bucket_count, const int* __restrict__ staged,
                             int2* __restrict__ rowbounds, float* __restrict__ dinv,
                             int* __restrict__ csr, const float* __restrict__ x,
                             unsigned short* __restrict__ xb) {
    __shared__ int sl[STRIDE];     // 18.4 KB bucket slice
    __shared__ int image[CAP];     // 20.5 KB csr image (src<<6)
    __shared__ int cnt[256];
    __shared__ int scn[256];
    __shared__ int loff[256];
    __shared__ int cursor[256];
    __shared__ int totalS;
    int b = blockIdx.x;
    int tid = threadIdx.x;
    int count = bucket_count[b];
    const int* st = staged + b * STRIDE;
    cnt[tid] = 0;
    cursor[tid] = 0;
    for (int i = tid; i < count; i += 256) sl[i] = st[i];
    __syncthreads();
    for (int i = tid; i < count; i += 256) atomicAdd(&cnt[(sl[i] >> 17) & 255], 1);
    __syncthreads();
    int deg = cnt[tid];
    int degp = (deg + 3) & ~3;  // pad to x4
    scn[tid] = degp;
    __syncthreads();
    for (int off = 1; off < 256; off <<= 1) {
        int u = (tid >= off) ? scn[tid - off] : 0;
        __syncthreads();
        scn[tid] += u;
        __syncthreads();
    }
    int lo = scn[tid] - degp;
    loff[tid] = lo;
    int nbase = (b << 8) + tid;
    int gb = b * CSR_STRIDE;
    rowbounds[nbase] = make_int2(gb + lo, gb + lo + degp);
    float dv = rsqrtf((float)deg + 1.0f);
    dinv[nbase] = dv;
    if (tid == 255) totalS = lo + degp;
    {
        const float* xp = x + nbase * IN_CH;
        unsigned o[8];
#pragma unroll
        for (int k = 0; k < 6; k++) o[k] = pack2bf(dv * xp[2 * k], dv * xp[2 * k + 1]);
        o[6] = 0; o[7] = 0;
        uint4* dstp = (uint4*)(xb + nbase * 16);
        dstp[0] = make_uint4(o[0], o[1], o[2], o[3]);
        dstp[1] = make_uint4(o[4], o[5], o[6], o[7]);
    }
    if (b == 0 && tid < 2)  // zero row N_NODES of xb (pad target)
        ((uint4*)(xb + (size_t)N_NODES * 16))[tid] = make_uint4(0, 0, 0, 0);
    __syncthreads();
    for (int i = tid; i < count; i += 256) {
        int rec = sl[i];
        int s = rec & 0x1FFFF;
        int dq = (rec >> 17) & 255;
        int p = loff[dq] + atomicAdd(&cursor[dq], 1);
        int val = s << 6;  // byte off into 64B fp8 row | >>2: x16 bf16 row
        if (p < CAP) image[p] = val;
        else csr[gb + p] = val;
    }
    __syncthreads();
    int padval = N_NODES << 6;  // zero row
    for (int p = loff[tid] + deg; p < loff[tid] + degp; p++) {
        if (p < CAP) image[p] = padval;
        else csr[gb + p] = padval;
    }
    __syncthreads();
    int lim = totalS < CAP ? totalS : CAP;
    int* dstp = csr + gb;
    for (int i = tid; i < lim; i += 256) dstp[i] = image[i];
}

// ---- fused layer-1 gather + w1 + w2, register-tiled: 64 nodes/block ----
// R3: no sW2 LDS copy (W2 read from global/L1 in phase 2); LDS 23.5KB -> 6 blocks/CU.
__global__ __launch_bounds__(256, 6)
void w1w2_kernel(const int2* __restrict__ rowbounds, const int* __restrict__ csr,
                 const float* __restrict__ dinv, const unsigned short* __restrict__ xb,
                 const float* __restrict__ W1, const float* __restrict__ b1,
                 const float* __restrict__ W2, unsigned int* __restrict__ hout) {
    __shared__ float sW1[IN_CH * HID];     // 3 KB
    __shared__ float sA[64 * 17];          // 4.25 KB (padded pitch 17)
    __shared__ float sh1t[HID * 65];       // 16.25 KB: h1^T [ch][node], pitch 65
    int tid = threadIdx.x;
    for (int i = tid; i < IN_CH * HID; i += 256) sW1[i] = W1[i];
    int node0 = blockIdx.x * 64;
    {   // gather phase: 4 thr/node = 2 edge-halves x 2 ch-halves
        int nl = tid >> 2;
        int node = node0 + nl;
        int p = tid & 1, qoff = 8 * p;  // shorts
        int2 rb = rowbounds[node];
        float dn = dinv[node];          // hoisted: issue early
        uint4 su = make_uint4(0, 0, 0, 0);
        if (!(tid & 2)) su = *(const uint4*)(xb + node * 16 + qoff);  // hoisted
        int len = rb.y - rb.x;
        int hlen = (len >> 3) << 2;     // first half, mult of 4
        int beg = (tid & 2) ? rb.x + hlen : rb.x;
        int end = (tid & 2) ? rb.y : rb.x + hlen;
        f32x2 a0[4] = {{0, 0}, {0, 0}, {0, 0}, {0, 0}};
        f32x2 a1[4] = {{0, 0}, {0, 0}, {0, 0}, {0, 0}};
        f32x2 a2[4] = {{0, 0}, {0, 0}, {0, 0}, {0, 0}};
        f32x2 a3[4] = {{0, 0}, {0, 0}, {0, 0}, {0, 0}};
        for (int j = beg; j < end; j += 4) {  // padded x4: no remainder
            int4 e = *(const int4*)(csr + j);
            uint4 u0 = *(const uint4*)(xb + (e.x >> 2) + qoff);
            uint4 u1 = *(const uint4*)(xb + (e.y >> 2) + qoff);
            uint4 u2 = *(const uint4*)(xb + (e.z >> 2) + qoff);
            uint4 u3 = *(const uint4*)(xb + (e.w >> 2) + qoff);
            a0[0] += (f32x2){bflo(u0.x), bfhi(u0.x)};
            a0[1] += (f32x2){bflo(u0.y), bfhi(u0.y)};
            a0[2] += (f32x2){bflo(u0.z), bfhi(u0.z)};
            a0[3] += (f32x2){bflo(u0.w), bfhi(u0.w)};
            a1[0] += (f32x2){bflo(u1.x), bfhi(u1.x)};
            a1[1] += (f32x2){bflo(u1.y), bfhi(u1.y)};
            a1[2] += (f32x2){bflo(u1.z), bfhi(u1.z)};
            a1[3] += (f32x2){bflo(u1.w), bfhi(u1.w)};
            a2[0] += (f32x2){bflo(u2.x), bfhi(u2.x)};
            a2[1] += (f32x2){bflo(u2.y), bfhi(u2.y)};
            a2[2] += (f32x2){bflo(u2.z), bfhi(u2.z)};
            a2[3] += (f32x2){bflo(u2.w), bfhi(u2.w)};
            a3[0] += (f32x2){bflo(u3.x), bfhi(u3.x)};
            a3[1] += (f32x2){bflo(u3.y), bfhi(u3.y)};
            a3[2] += (f32x2){bflo(u3.z), bfhi(u3.z)};
            a3[3] += (f32x2){bflo(u3.w), bfhi(u3.w)};
        }
        f32x2 s0 = (a0[0] + a1[0]) + (a2[0] + a3[0]);
        f32x2 s1 = (a0[1] + a1[1]) + (a2[1] + a3[1]);
        f32x2 s2 = (a0[2] + a1[2]) + (a2[2] + a3[2]);
        f32x2 s3 = (a0[3] + a1[3]) + (a2[3] + a3[3]);
        s0[0] += __shfl_xor(s0[0], 2); s0[1] += __shfl_xor(s0[1], 2);
        s1[0] += __shfl_xor(s1[0], 2); s1[1] += __shfl_xor(s1[1], 2);
        s2[0] += __shfl_xor(s2[0], 2); s2[1] += __shfl_xor(s2[1], 2);
        s3[0] += __shfl_xor(s3[0], 2); s3[1] += __shfl_xor(s3[1], 2);
        if (!(tid & 2)) {
            s0 += (f32x2){bflo(su.x), bfhi(su.x)};
            s1 += (f32x2){bflo(su.y), bfhi(su.y)};
            s2 += (f32x2){bflo(su.z), bfhi(su.z)};
            s3 += (f32x2){bflo(su.w), bfhi(su.w)};
            float* dp = &sA[nl * 17 + qoff];
            dp[0] = dn * s0[0]; dp[1] = dn * s0[1];
            dp[2] = dn * s1[0]; dp[3] = dn * s1[1];
            dp[4] = dn * s2[0]; dp[5] = dn * s2[1];
            dp[6] = dn * s3[0]; dp[7] = dn * s3[1];
        }
    }
    __syncthreads();
    // phase 1 (W1): wave w computes 16-node x 64-ch tile; lane = channel
    int w = tid >> 6, c = tid & 63;
    float bc = b1[c];
#pragma unroll
    for (int it = 0; it < 4; it++) {
        int n0 = w * 16 + it * 4;
        float a0 = bc, a1 = bc, a2 = bc, a3 = bc;
#pragma unroll
        for (int k = 0; k < IN_CH; k++) {
            float wv = sW1[k * HID + c];
            a0 += sA[(n0 + 0) * 17 + k] * wv;  // sA reads broadcast per wave
            a1 += sA[(n0 + 1) * 17 + k] * wv;
            a2 += sA[(n0 + 2) * 17 + k] * wv;
            a3 += sA[(n0 + 3) * 17 + k] * wv;
        }
        float4 o = make_float4(fmaxf(a0, 0.0f), fmaxf(a1, 0.0f),
                               fmaxf(a2, 0.0f), fmaxf(a3, 0.0f));
        *(float4*)&sh1t[c * 65 + n0] = o;  // transposed: [ch][node]
    }
    __syncthreads();
    // phase 2 (W2): thread = 4 nodes x 4 ch; W2 from global (L1-resident 16KB)
    int nq = tid >> 4, c4 = (tid & 15) * 4;
    float4 a0 = {0, 0, 0, 0}, a1 = {0, 0, 0, 0}, a2 = {0, 0, 0, 0}, a3 = {0, 0, 0, 0};
#pragma unroll 4
    for (int k = 0; k < HID; k++) {
        float4 wv = *(const float4*)&W2[k * HID + c4];
        float4 hv = *(const float4*)&sh1t[k * 65 + nq * 4];  // 4 nodes' h1[k]
        a0.x += hv.x * wv.x; a0.y += hv.x * wv.y; a0.z += hv.x * wv.z; a0.w += hv.x * wv.w;
        a1.x += hv.y * wv.x; a1.y += hv.y * wv.y; a1.z += hv.y * wv.z; a1.w += hv.y * wv.w;
        a2.x += hv.z * wv.x; a2.y += hv.z * wv.y; a2.z += hv.z * wv.z; a2.w += hv.z * wv.w;
        a3.x += hv.w * wv.x; a3.y += hv.w * wv.y; a3.z += hv.w * wv.z; a3.w += hv.w * wv.w;
    }
    int nb = node0 + nq * 4;
    float dv0 = dinv[nb + 0], dv1 = dinv[nb + 1], dv2 = dinv[nb + 2], dv3 = dinv[nb + 3];
    unsigned int p0 = (unsigned int)__builtin_amdgcn_cvt_pk_fp8_f32(dv0 * a0.x, dv0 * a0.y, 0, false);
    p0 = (unsigned int)__builtin_amdgcn_cvt_pk_fp8_f32(dv0 * a0.z, dv0 * a0.w, (int)p0, true);
    unsigned int p1 = (unsigned int)__builtin_amdgcn_cvt_pk_fp8_f32(dv1 * a1.x, dv1 * a1.y, 0, false);
    p1 = (unsigned int)__builtin_amdgcn_cvt_pk_fp8_f32(dv1 * a1.z, dv1 * a1.w, (int)p1, true);
    unsigned int p2 = (unsigned int)__builtin_amdgcn_cvt_pk_fp8_f32(dv2 * a2.x, dv2 * a2.y, 0, false);
    p2 = (unsigned int)__builtin_amdgcn_cvt_pk_fp8_f32(dv2 * a2.z, dv2 * a2.w, (int)p2, true);
    unsigned int p3 = (unsigned int)__builtin_amdgcn_cvt_pk_fp8_f32(dv3 * a3.x, dv3 * a3.y, 0, false);
    p3 = (unsigned int)__builtin_amdgcn_cvt_pk_fp8_f32(dv3 * a3.z, dv3 * a3.w, (int)p3, true);
    int cl = c4 >> 2;
    hout[(nb + 0) * 16 + cl] = p0;   // per-instruction: 64B runs, fully coalesced
    hout[(nb + 1) * 16 + cl] = p1;
    hout[(nb + 2) * 16 + cl] = p2;
    hout[(nb + 3) * 16 + cl] = p3;
    if (blockIdx.x == 0 && tid < 16)  // zero row N_NODES (pad target)
        hout[(size_t)N_NODES * 16 + tid] = 0;
}

// ---- layer-2 fp8 gather body: 4 thr/node, uint4 (16 ch); 8 edges in flight ----
__device__ __forceinline__ void add_fp8q(f32x2* a, uint4 u) {
    a[0] += __builtin_amdgcn_cvt_pk_f32_fp8((int)u.x, false);
    a[1] += __builtin_amdgcn_cvt_pk_f32_fp8((int)u.x, true);
    a[2] += __builtin_amdgcn_cvt_pk_f32_fp8((int)u.y, false);
    a[3] += __builtin_amdgcn_cvt_pk_f32_fp8((int)u.y, true);
    a[4] += __builtin_amdgcn_cvt_pk_f32_fp8((int)u.z, false);
    a[5] += __builtin_amdgcn_cvt_pk_f32_fp8((int)u.z, true);
    a[6] += __builtin_amdgcn_cvt_pk_f32_fp8((int)u.w, false);
    a[7] += __builtin_amdgcn_cvt_pk_f32_fp8((int)u.w, true);
}

__device__ __forceinline__ void agg_body16(int beg, int end, const int* __restrict__ csr,
                                           const unsigned char* __restrict__ h,
                                           int qoff, float* r) {
    f32x2 a0[8] = {{0, 0}, {0, 0}, {0, 0}, {0, 0}, {0, 0}, {0, 0}, {0, 0}, {0, 0}};
    f32x2 a1[8] = {{0, 0}, {0, 0}, {0, 0}, {0, 0}, {0, 0}, {0, 0}, {0, 0}, {0, 0}};
    int j = beg;
    for (; j + 8 <= end; j += 8) {  // 8 edges in flight
        int4 ea = *(const int4*)(csr + j);
        int4 eb = *(const int4*)(csr + j + 4);
        uint4 u0 = *(const uint4*)(h + ea.x + qoff);
        uint4 u1 = *(const uint4*)(h + ea.y + qoff);
        uint4 u2 = *(const uint4*)(h + ea.z + qoff);
        uint4 u3 = *(const uint4*)(h + ea.w + qoff);
        uint4 u4 = *(const uint4*)(h + eb.x + qoff);
        uint4 u5 = *(const uint4*)(h + eb.y + qoff);
        uint4 u6 = *(const uint4*)(h + eb.z + qoff);
        uint4 u7 = *(const uint4*)(h + eb.w + qoff);
        add_fp8q(a0, u0); add_fp8q(a1, u1); add_fp8q(a0, u2); add_fp8q(a1, u3);
        add_fp8q(a0, u4); add_fp8q(a1, u5); add_fp8q(a0, u6); add_fp8q(a1, u7);
    }
    if (j < end) {  // exactly 4 padded edges remain
        int4 ea = *(const int4*)(csr + j);
        uint4 u0 = *(const uint4*)(h + ea.x + qoff);
        uint4 u1 = *(const uint4*)(h + ea.y + qoff);
        uint4 u2 = *(const uint4*)(h + ea.z + qoff);
        uint4 u3 = *(const uint4*)(h + ea.w + qoff);
        add_fp8q(a0, u0); add_fp8q(a1, u1); add_fp8q(a0, u2); add_fp8q(a1, u3);
    }
#pragma unroll
    for (int k = 0; k < 8; k++) {
        f32x2 s = a0[k] + a1[k];
        r[2 * k] = s[0];
        r[2 * k + 1] = s[1];
    }
}

// ---- layer-2 gather-aggregate + relu + fused mean-pool (run-length flush) ----
__global__ void agg_pool_kernel(const int2* __restrict__ rowbounds, const int* __restrict__ csr,
                                const float* __restrict__ dinv,
                                const unsigned char* __restrict__ h,
                                const float* __restrict__ b, const int* __restrict__ batch,
                                float* __restrict__ pool, float* __restrict__ gcnt) {
    __shared__ float red[64][HID + 4];  // 17 KB, padded pitch kills bank conflicts
    __shared__ int gids[64];
    int tid = threadIdx.x;
    int w = tid >> 6, lane = tid & 63, sub = lane >> 2, q = lane & 3;
    int qoff = 16 * q;  // byte offset in 64B fp8 row == channel offset
    int node = (blockIdx.x * 4 + w) * 16 + sub;
    int2 rb = rowbounds[node];
    float dn = dinv[node];
    float r[16];
    agg_body16(rb.x, rb.y, csr, h, qoff, r);
    uint4 su = *(const uint4*)(h + node * HID + qoff);  // hB' already has dinv_s
    f32x2 s[8];
    s[0] = __builtin_amdgcn_cvt_pk_f32_fp8((int)su.x, false);
    s[1] = __builtin_amdgcn_cvt_pk_f32_fp8((int)su.x, true);
    s[2] = __builtin_amdgcn_cvt_pk_f32_fp8((int)su.y, false);
    s[3] = __builtin_amdgcn_cvt_pk_f32_fp8((int)su.y, true);
    s[4] = __builtin_amdgcn_cvt_pk_f32_fp8((int)su.z, false);
    s[5] = __builtin_amdgcn_cvt_pk_f32_fp8((int)su.z, true);
    s[6] = __builtin_amdgcn_cvt_pk_f32_fp8((int)su.w, false);
    s[7] = __builtin_amdgcn_cvt_pk_f32_fp8((int)su.w, true);
    int nl = w * 16 + sub;
    float* rp = &red[nl][qoff];
#pragma unroll
    for (int k = 0; k < 4; k++) {
        float4 bv = *(const float4*)&b[qoff + 4 * k];
        rp[4 * k + 0] = fmaxf(dn * (r[4 * k + 0] + s[2 * k][0]) + bv.x, 0.0f);
        rp[4 * k + 1] = fmaxf(dn * (r[4 * k + 1] + s[2 * k][1]) + bv.y, 0.0f);
        rp[4 * k + 2] = fmaxf(dn * (r[4 * k + 2] + s[2 * k + 1][0]) + bv.z, 0.0f);
        rp[4 * k + 3] = fmaxf(dn * (r[4 * k + 3] + s[2 * k + 1][1]) + bv.w, 0.0f);
    }
    if (q == 0) gids[nl] = batch[node];
    __syncthreads();
    if (tid < 64) {  // wave 0: run-length reduce 64 nodes (batch sorted)
        int c = tid;
        float acc = 0.0f;
        int cur = gids[0], cnt = 0;
        for (int n = 0; n < 64; n++) {
            int g = gids[n];
            if (g != cur) {
                atomicAdd(&pool[cur * HID + c], acc);
                if (c == 0) atomicAdd(&gcnt[cur], (float)cnt);
                acc = 0.0f; cnt = 0; cur = g;
            }
            acc += red[n][c];
            cnt++;
        }
        atomicAdd(&pool[cur * HID + c], acc);
        if (c == 0) atomicAdd(&gcnt[cur], (float)cnt);
    }
}

// ---- final: out = sigmoid((pool/cnt) @ Wfc + bfc) ----
__global__ void final_kernel(const float* __restrict__ pool, const float* __restrict__ gcnt,
                             const float* __restrict__ Wfc, const float* __restrict__ bfc,
                             float* __restrict__ out) {
    int idx = blockIdx.x * 256 + threadIdx.x;
    if (idx >= N_GRAPHS * OUT_CH) return;
    int g = idx >> 2, o = idx & 3;
    float inv = 1.0f / fmaxf(gcnt[g], 1.0f);
    float acc = bfc[o];
#pragma unroll
    for (int k = 0; k < HID; k++) acc += pool[g * HID + k] * inv * Wfc[k * OUT_CH + o];
    out[idx] = 1.0f / (1.0f + expf(-acc));
}

extern "C" void kernel_launch(void* const* d_in, const int* in_sizes, int n_in,
                              void* d_out, int out_size, void* d_ws, size_t ws_size,
                              hipStream_t stream) {
    const float* x   = (const float*)d_in[0];
    const int* eidx  = (const int*)d_in[1];
    const int* batch = (const int*)d_in[2];
    const float* W1  = (const float*)d_in[3];
    const float* b1  = (const float*)d_in[4];
    const float* W2  = (const float*)d_in[5];
    const float* b2  = (const float*)d_in[6];
    const float* Wfc = (const float*)d_in[7];
    const float* bfc = (const float*)d_in[8];
    float* out = (float*)d_out;

    const int* src = eidx;
    const int* dst = eidx + N_EDGES;

    // workspace layout (~37 MB)
    unsigned char* hB = (unsigned char*)d_ws;                 // 8.4 MB fp8 (+1 zero row)
    int*   csr    = (int*)(hB + (size_t)(N_NODES + 1) * HID); // 10.5 MB src<<6
    int*   staged = csr + (size_t)NBUCK * CSR_STRIDE;         // 9.4 MB bucket-strided
    float* dinv   = (float*)(staged + (size_t)NBUCK * STRIDE); // 512 KB
    int2*  rowbounds = (int2*)(dinv + N_NODES);               // 1 MB
    int*   bucket_count = (int*)(rowbounds + N_NODES);        // 2 KB
    float* pool   = (float*)(bucket_count + NBUCK);           // 512 KB
    float* gcnt   = pool + N_GRAPHS * HID;                    // 8 KB
    unsigned short* xb = (unsigned short*)(gcnt + N_GRAPHS);  // 4 MB bf16 [N+1,16]

    // single memset: bucket_count | pool | gcnt are contiguous
    hipMemsetAsync(bucket_count, 0,
                   (size_t)(NBUCK + N_GRAPHS * HID + N_GRAPHS) * 4, stream);

    // CSR build: bucket sort -> fused count/scan/place (+prescaled xcast)
    bucket_kernel<<<N_EDGES / CHUNK, 1024, 0, stream>>>(src, dst, bucket_count, staged);
    build_kernel<<<NBUCK, 256, 0, stream>>>(bucket_count, staged, rowbounds, dinv, csr, x, xb);

    // layer 1: fused gather + register-tiled W1+W2 (h1 LDS-only) -> fp8 hB'
    w1w2_kernel<<<N_NODES / 64, 256, 0, stream>>>(rowbounds, csr, dinv, xb, W1, b1, W2,
                                                  (unsigned int*)hB);

    // layer 2: gather + pool
    agg_pool_kernel<<<N_NODES / 64, 256, 0, stream>>>(rowbounds, csr, dinv, hB, b2, batch,
                                                      pool, gcnt);

    // head
    final_kernel<<<(N_GRAPHS * OUT_CH + 255) / 256, 256, 0, stream>>>(pool, gcnt, Wfc, bfc, out);
}